// Round 1
// baseline (1904.561 us; speedup 1.0000x reference)
//
#include <hip/hip_runtime.h>
#include <hip/hip_bf16.h>
#include <math.h>

#define DM 1024
#define DS 16
#define DI 2048
#define NB 2
#define LL 2048
#define BL (NB*LL)

__device__ __forceinline__ float silu_f(float x){ return x / (1.f + __expf(-x)); }
__device__ __forceinline__ float softplus_f(float x){ return (x > 15.f) ? x : log1pf(__expf(x)); }

// C[M][N] = A[M][K] @ Bw[N][K]^T  (both operands K-contiguous row-major)
// EPI==1: v = softplus(v + bias[n])
template<int EPI>
__global__ __launch_bounds__(256) void gemm_nt(
    const float* __restrict__ A, const float* __restrict__ Bw,
    const float* __restrict__ bias, float* __restrict__ C,
    int M, int N, int K)
{
  __shared__ float As[16][128];
  __shared__ float Bs[16][128];
  const int t = threadIdx.x;
  const int tx = t & 15, ty = t >> 4;
  const int bm = blockIdx.y * 128, bn = blockIdx.x * 128;
  float acc[8][8] = {};
  const int lr0 = t >> 2;          // 0..63
  const int lr1 = lr0 + 64;        // 64..127
  const int lc = (t & 3) * 4;      // 0,4,8,12

  for (int k0 = 0; k0 < K; k0 += 16) {
    float4 a0 = *(const float4*)&A [(size_t)(bm + lr0)*K + k0 + lc];
    float4 a1 = *(const float4*)&A [(size_t)(bm + lr1)*K + k0 + lc];
    float4 b0 = *(const float4*)&Bw[(size_t)(bn + lr0)*K + k0 + lc];
    float4 b1 = *(const float4*)&Bw[(size_t)(bn + lr1)*K + k0 + lc];
    __syncthreads();
    As[lc+0][lr0]=a0.x; As[lc+1][lr0]=a0.y; As[lc+2][lr0]=a0.z; As[lc+3][lr0]=a0.w;
    As[lc+0][lr1]=a1.x; As[lc+1][lr1]=a1.y; As[lc+2][lr1]=a1.z; As[lc+3][lr1]=a1.w;
    Bs[lc+0][lr0]=b0.x; Bs[lc+1][lr0]=b0.y; Bs[lc+2][lr0]=b0.z; Bs[lc+3][lr0]=b0.w;
    Bs[lc+0][lr1]=b1.x; Bs[lc+1][lr1]=b1.y; Bs[lc+2][lr1]=b1.z; Bs[lc+3][lr1]=b1.w;
    __syncthreads();
    #pragma unroll
    for (int kk = 0; kk < 16; kk++) {
      float4 av0 = *(const float4*)&As[kk][ty*8];
      float4 av1 = *(const float4*)&As[kk][ty*8+4];
      float4 bv0 = *(const float4*)&Bs[kk][tx*8];
      float4 bv1 = *(const float4*)&Bs[kk][tx*8+4];
      float a[8] = {av0.x,av0.y,av0.z,av0.w,av1.x,av1.y,av1.z,av1.w};
      float b[8] = {bv0.x,bv0.y,bv0.z,bv0.w,bv1.x,bv1.y,bv1.z,bv1.w};
      #pragma unroll
      for (int i=0;i<8;i++)
        #pragma unroll
        for (int j=0;j<8;j++)
          acc[i][j] += a[i]*b[j];
    }
  }
  #pragma unroll
  for (int i=0;i<8;i++){
    size_t m = bm + ty*8 + i;
    float* crow = C + m*(size_t)N + bn + tx*8;
    float outv[8];
    #pragma unroll
    for (int j=0;j<8;j++){
      float v = acc[i][j];
      if (EPI==1) v = softplus_f(v + bias[bn + tx*8 + j]);
      outv[j] = v;
    }
    *(float4*)&crow[0] = make_float4(outv[0],outv[1],outv[2],outv[3]);
    *(float4*)&crow[4] = make_float4(outv[4],outv[5],outv[6],outv[7]);
  }
}

// causal depthwise conv (k=4) + bias + SiLU over the first DI cols of xz
__global__ __launch_bounds__(256) void conv_silu_k(
    const float* __restrict__ xz, const float* __restrict__ cw,
    const float* __restrict__ cb, float* __restrict__ xa)
{
  int idx = blockIdx.x * 256 + threadIdx.x;       // over BL*DI
  int d  = idx & (DI-1);
  int bl = idx >> 11;                             // DI = 2048
  int l  = bl & (LL-1);
  float acc = cb[d];
  #pragma unroll
  for (int k = 0; k < 4; k++){
    int ls = l - 3 + k;
    if (ls >= 0)
      acc += xz[((size_t)(bl - l + ls))*(2*DI) + d] * cw[d*4 + k];
  }
  xa[idx] = silu_f(acc);
}

// bc[m][0..31] = xa[m,:] @ x_proj_w[0..31,:]^T  (one row per block)
__global__ __launch_bounds__(256) void bc_k(
    const float* __restrict__ xa, const float* __restrict__ w, float* __restrict__ bc)
{
  const int m = blockIdx.x;
  const int t = threadIdx.x;
  const int nn = t & 31, ch = t >> 5;
  const float* xr = xa + (size_t)m*DI + ch*256;
  const float* wr = w + (size_t)nn*DI + ch*256;
  float s = 0.f;
  #pragma unroll 8
  for (int k = 0; k < 256; k++) s += xr[k]*wr[k];
  __shared__ float red[8][32];
  red[ch][nn] = s;
  __syncthreads();
  if (t < 32){
    float v = 0.f;
    #pragma unroll
    for (int c = 0; c < 8; c++) v += red[c][t];
    bc[(size_t)m*32 + t] = v;
  }
}

// selective scan over L, fused with +u*D and *silu(z) gating
// block: 256 threads = 16 d-channels x 16 states; grid: NB * (DI/16)
__global__ __launch_bounds__(256) void scan_k(
    const float* __restrict__ xa, const float* __restrict__ delta,
    const float* __restrict__ bc, const float* __restrict__ A_log,
    const float* __restrict__ Dp, const float* __restrict__ xz,
    float* __restrict__ y)
{
  const int blk = blockIdx.x;
  const int b  = blk >> 7;
  const int d0 = (blk & 127) * 16;
  const int t = threadIdx.x;
  const int n = t & 15, dl = t >> 4;
  const int d = d0 + dl;
  const float Ac = -__expf(A_log[d*DS + n]);
  const float Dv = Dp[d];
  float h = 0.f;
  __shared__ float s_du[16][3][16];   // [l-chunk][delta|u|z][d]
  __shared__ float s_bc[16][32];      // [l-chunk][B(16),C(16)]
  const int li = t >> 4, q = t & 15;

  for (int l0 = 0; l0 < LL; l0 += 16) {
    __syncthreads();
    {
      size_t row = (size_t)(b*LL + l0 + li);
      s_du[li][0][q] = delta[row*DI + d0 + q];
      s_du[li][1][q] = xa[row*DI + d0 + q];
      s_du[li][2][q] = xz[row*(2*DI) + DI + d0 + q];   // z
    }
    #pragma unroll
    for (int e = t; e < 512; e += 256){
      int ii = e >> 5, j = e & 31;
      s_bc[ii][j] = bc[(size_t)(b*LL + l0 + ii)*32 + j];
    }
    __syncthreads();
    #pragma unroll
    for (int i = 0; i < 16; i++){
      float dlt = s_du[i][0][dl];
      float u   = s_du[i][1][dl];
      float Bv  = s_bc[i][n];
      float Cv  = s_bc[i][16+n];
      float dA  = __expf(dlt * Ac);
      h = dA*h + (dlt*u)*Bv;
      float c = h * Cv;
      c += __shfl_xor(c, 1);
      c += __shfl_xor(c, 2);
      c += __shfl_xor(c, 4);
      c += __shfl_xor(c, 8);
      if (n == 0){
        float zz = s_du[i][2][dl];
        y[(size_t)(b*LL + l0 + i)*DI + d] = (c + u*Dv) * silu_f(zz);
      }
    }
  }
}

extern "C" void kernel_launch(void* const* d_in, const int* in_sizes, int n_in,
                              void* d_out, int out_size, void* d_ws, size_t ws_size,
                              hipStream_t stream)
{
  const float* x    = (const float*)d_in[0];
  const float* Win  = (const float*)d_in[1];
  const float* cw   = (const float*)d_in[2];
  const float* cb   = (const float*)d_in[3];
  const float* Wxp  = (const float*)d_in[4];
  const float* Wdt  = (const float*)d_in[5];
  const float* bdt  = (const float*)d_in[6];
  const float* Alog = (const float*)d_in[7];
  const float* Dp   = (const float*)d_in[8];
  const float* Wout = (const float*)d_in[9];
  float* out = (float*)d_out;

  float* ws    = (float*)d_ws;
  float* xz    = ws;                         // BL * 4096
  float* xa    = xz + (size_t)BL*2*DI;       // BL * 2048
  float* dlt   = xa + (size_t)BL*DI;         // BL * 2048
  float* bcb   = dlt + (size_t)BL*DI;        // BL * 32
  float* yb    = bcb + (size_t)BL*32;        // BL * 2048

  dim3 blk(256);
  // 1) xz = x @ in_proj_w^T            [4096 x 4096], K=1024
  gemm_nt<0><<<dim3((2*DI)/128, BL/128), blk, 0, stream>>>(x, Win, nullptr, xz, BL, 2*DI, DM);
  // 2) x_act = silu(causal_conv(x_ssm))
  conv_silu_k<<<dim3((BL*DI)/256), blk, 0, stream>>>(xz, cw, cb, xa);
  // 3) delta = softplus(x_act @ dt_proj_w^T + b)   [4096 x 2048], K=2048
  gemm_nt<1><<<dim3(DI/128, BL/128), blk, 0, stream>>>(xa, Wdt, bdt, dlt, BL, DI, DI);
  // 4) bc = x_act @ x_proj_w^T         [4096 x 32]
  bc_k<<<dim3(BL), blk, 0, stream>>>(xa, Wxp, bcb);
  // 5) selective scan + D skip + silu(z) gate -> y  [4096 x 2048]
  scan_k<<<dim3(NB*(DI/16)), blk, 0, stream>>>(xa, dlt, bcb, Alog, Dp, xz, yb);
  // 6) out = y @ out_proj_w^T          [4096 x 1024], K=2048
  gemm_nt<0><<<dim3(DM/128, BL/128), blk, 0, stream>>>(yb, Wout, nullptr, out, BL, DM, DI);
}

// Round 2
// 423.324 us; speedup vs baseline: 4.4991x; 4.4991x over previous
//
#include <hip/hip_runtime.h>
#include <hip/hip_bf16.h>
#include <math.h>

#define DM 1024
#define DS 16
#define DI 2048
#define NB 2
#define LL 2048
#define BL (NB*LL)
#define LC 32
#define NC (LL/LC)   // 64

typedef __attribute__((ext_vector_type(8))) short short8;
typedef __attribute__((ext_vector_type(8))) unsigned short ushort8;
typedef __attribute__((ext_vector_type(4))) float f32x4;

__device__ __forceinline__ float silu_f(float x){ return x / (1.f + __expf(-x)); }
__device__ __forceinline__ float softplus_f(float x){ return (x > 15.f) ? x : log1pf(__expf(x)); }
__device__ __forceinline__ unsigned short f2bf(float f){
  unsigned u = __float_as_uint(f);
  u += 0x7fff + ((u >> 16) & 1);
  return (unsigned short)(u >> 16);
}
__device__ __forceinline__ float bf2f(unsigned short v){
  return __uint_as_float(((unsigned)v) << 16);
}

// ---------------- fp32 -> bf16 convert (8 elems/thread) ----------------
__global__ __launch_bounds__(256) void f2b_k(const float* __restrict__ src,
                                             unsigned short* __restrict__ dst, int n)
{
  int i = (blockIdx.x * 256 + threadIdx.x) * 8;
  if (i >= n) return;
  float4 v0 = *(const float4*)&src[i];
  float4 v1 = *(const float4*)&src[i + 4];
  ushort8 o;
  o[0]=f2bf(v0.x); o[1]=f2bf(v0.y); o[2]=f2bf(v0.z); o[3]=f2bf(v0.w);
  o[4]=f2bf(v1.x); o[5]=f2bf(v1.y); o[6]=f2bf(v1.z); o[7]=f2bf(v1.w);
  *(ushort8*)&dst[i] = o;
}

// ---------------- bf16 MFMA GEMM:  C[M][N] = A[M][K] @ Bw[N][K]^T ------
// 128x128 tile, BK=32, 4 waves, wave tile 64x64 (4x4 frags of 16x16x32)
// EPI==1: v = softplus(v + bias[col])
template<int EPI>
__global__ __launch_bounds__(256) void gemm_bt_mfma(
    const unsigned short* __restrict__ A, const unsigned short* __restrict__ Bw,
    const float* __restrict__ bias, float* __restrict__ C,
    int M, int N, int K)
{
  __shared__ unsigned short As[128 * 32];
  __shared__ unsigned short Bs[128 * 32];
  const int t = threadIdx.x;
  const int wid = t >> 6, lane = t & 63;
  const int bm = blockIdx.y * 128, bn = blockIdx.x * 128;
  const int wm = (wid >> 1) * 64, wn = (wid & 1) * 64;
  f32x4 acc[4][4] = {};

  const int srow = (lane >> 2);          // 0..15 within segment
  const int scol = (lane & 3) * 8;       // k-elem offset of this lane's 16B

  for (int k0 = 0; k0 < K; k0 += 32) {
    __syncthreads();
    #pragma unroll
    for (int q = 0; q < 2; q++) {
      int seg = wid * 2 + q;             // 0..7, wave-uniform
      int row = seg * 16 + srow;
      __builtin_amdgcn_global_load_lds(
          (const __attribute__((address_space(1))) void*)(A + (size_t)(bm + row) * K + k0 + scol),
          (__attribute__((address_space(3))) void*)(As + seg * 512), 16, 0, 0);
      __builtin_amdgcn_global_load_lds(
          (const __attribute__((address_space(1))) void*)(Bw + (size_t)(bn + row) * K + k0 + scol),
          (__attribute__((address_space(3))) void*)(Bs + seg * 512), 16, 0, 0);
    }
    __syncthreads();
    short8 af[4], bfr[4];
    #pragma unroll
    for (int i = 0; i < 4; i++) {
      af[i]  = *(const short8*)&As[(wm + i * 16 + (lane & 15)) * 32 + (lane >> 4) * 8];
      bfr[i] = *(const short8*)&Bs[(wn + i * 16 + (lane & 15)) * 32 + (lane >> 4) * 8];
    }
    #pragma unroll
    for (int i = 0; i < 4; i++)
      #pragma unroll
      for (int j = 0; j < 4; j++)
        acc[i][j] = __builtin_amdgcn_mfma_f32_16x16x32_bf16(af[i], bfr[j], acc[i][j], 0, 0, 0);
  }
  #pragma unroll
  for (int i = 0; i < 4; i++) {
    #pragma unroll
    for (int j = 0; j < 4; j++) {
      int col = bn + wn + j * 16 + (lane & 15);
      #pragma unroll
      for (int r = 0; r < 4; r++) {
        int row = bm + wm + i * 16 + (lane >> 4) * 4 + r;
        float v = acc[i][j][r];
        if (EPI == 1) v = softplus_f(v + bias[col]);
        C[(size_t)row * N + col] = v;
      }
    }
  }
}

// ---------------- causal depthwise conv (k=4) + bias + SiLU -> bf16 ----
__global__ __launch_bounds__(256) void conv_silu_k(
    const float* __restrict__ xz, const float* __restrict__ cw,
    const float* __restrict__ cb, unsigned short* __restrict__ xa)
{
  int idx = blockIdx.x * 256 + threadIdx.x;       // over BL*DI
  int d  = idx & (DI - 1);
  int bl = idx >> 11;
  int l  = bl & (LL - 1);
  float acc = cb[d];
  #pragma unroll
  for (int k = 0; k < 4; k++) {
    int ls = l - 3 + k;
    if (ls >= 0)
      acc += xz[((size_t)(bl - l + ls)) * (2 * DI) + d] * cw[d * 4 + k];
  }
  xa[idx] = f2bf(silu_f(acc));
}

// ---------------- bc = xa @ x_proj_w^T  (N=32) -------------------------
__global__ __launch_bounds__(256) void bc_k(
    const unsigned short* __restrict__ xa, const unsigned short* __restrict__ w,
    float* __restrict__ bc)
{
  const int m = blockIdx.x;
  const int t = threadIdx.x;
  const int nn = t & 31, ch = t >> 5;
  const unsigned short* xr = xa + (size_t)m * DI + ch * 256;
  const unsigned short* wr = w + (size_t)nn * DI + ch * 256;
  float s = 0.f;
  #pragma unroll 8
  for (int k = 0; k < 256; k++) s += bf2f(xr[k]) * bf2f(wr[k]);
  __shared__ float red[8][32];
  red[ch][nn] = s;
  __syncthreads();
  if (t < 32) {
    float v = 0.f;
    #pragma unroll
    for (int c = 0; c < 8; c++) v += red[c][t];
    bc[(size_t)m * 32 + t] = v;
  }
}

// ---------------- chunked selective scan -------------------------------
// pass 1: per (b, chunk, d): local scan (h0=0) -> final local state S[16], sum(delta)
__global__ __launch_bounds__(256) void scan_part1(
    const float* __restrict__ dlt, const unsigned short* __restrict__ xa,
    const float* __restrict__ bc, const float* __restrict__ A_log,
    float* __restrict__ S_arr, float* __restrict__ sumdlt)
{
  const int bid = blockIdx.x;           // NB*NC*8 = 1024
  const int b = bid >> 9;
  const int c = (bid >> 3) & (NC - 1);
  const int dg = bid & 7;
  const int t = threadIdx.x;
  const int d = dg * 256 + t;
  float Ac[16];
  #pragma unroll
  for (int n = 0; n < 16; n++) Ac[n] = -__expf(A_log[d * 16 + n]);
  __shared__ float sB[LC][16];
  for (int e = t; e < LC * 16; e += 256) {
    int l = e >> 4, n = e & 15;
    sB[l][n] = bc[(size_t)(b * LL + c * LC + l) * 32 + n];
  }
  __syncthreads();
  float h[16] = {};
  float sd = 0.f;
  size_t rowbase = (size_t)(b * LL + c * LC) * DI + d;
  for (int l = 0; l < LC; l++) {
    float dl = dlt[rowbase + (size_t)l * DI];
    float u  = bf2f(xa[rowbase + (size_t)l * DI]);
    float w = dl * u;
    sd += dl;
    #pragma unroll
    for (int n = 0; n < 16; n++) {
      float dA = __expf(dl * Ac[n]);
      h[n] = dA * h[n] + w * sB[l][n];
    }
  }
  float* Sp = S_arr + ((size_t)(b * NC + c) * DI + d) * 16;
  #pragma unroll
  for (int n = 0; n < 16; n++) Sp[n] = h[n];
  sumdlt[(size_t)(b * NC + c) * DI + d] = sd;
}

// pass 2: scan chunk summaries; overwrite S_arr with incoming state h_in per chunk
__global__ __launch_bounds__(256) void scan_combine(
    const float* __restrict__ A_log, const float* __restrict__ sumdlt,
    float* __restrict__ S_arr)
{
  int tid = blockIdx.x * 256 + threadIdx.x;   // NB*DI*16 = 65536
  int n = tid & 15;
  int d = (tid >> 4) & (DI - 1);
  int b = tid >> 15;
  float Ac = -__expf(A_log[d * 16 + n]);
  float h = 0.f;
  for (int c = 0; c < NC; c++) {
    size_t idx = ((size_t)(b * NC + c) * DI + d) * 16 + n;
    float S = S_arr[idx];
    float P = __expf(sumdlt[(size_t)(b * NC + c) * DI + d] * Ac);
    S_arr[idx] = h;
    h = P * h + S;
  }
}

// pass 3: recompute local scan with proper h_in, emit y = (h.C + u*D)*silu(z) in bf16
__global__ __launch_bounds__(256) void scan_part2(
    const float* __restrict__ dlt, const unsigned short* __restrict__ xa,
    const float* __restrict__ bc, const float* __restrict__ A_log,
    const float* __restrict__ Dp, const float* __restrict__ xz,
    const float* __restrict__ Hin, unsigned short* __restrict__ y)
{
  const int bid = blockIdx.x;
  const int b = bid >> 9;
  const int c = (bid >> 3) & (NC - 1);
  const int dg = bid & 7;
  const int t = threadIdx.x;
  const int d = dg * 256 + t;
  float Ac[16];
  #pragma unroll
  for (int n = 0; n < 16; n++) Ac[n] = -__expf(A_log[d * 16 + n]);
  __shared__ float sB[LC][16];
  __shared__ float sC[LC][16];
  for (int e = t; e < LC * 16; e += 256) {
    int l = e >> 4, n = e & 15;
    size_t row = (size_t)(b * LL + c * LC + l) * 32;
    sB[l][n] = bc[row + n];
    sC[l][n] = bc[row + 16 + n];
  }
  __syncthreads();
  float h[16];
  const float* Hp = Hin + ((size_t)(b * NC + c) * DI + d) * 16;
  #pragma unroll
  for (int n = 0; n < 16; n++) h[n] = Hp[n];
  const float Dv = Dp[d];
  size_t rowbase = (size_t)(b * LL + c * LC) * DI + d;
  for (int l = 0; l < LC; l++) {
    float dl = dlt[rowbase + (size_t)l * DI];
    float u  = bf2f(xa[rowbase + (size_t)l * DI]);
    float w = dl * u;
    float ya = 0.f;
    #pragma unroll
    for (int n = 0; n < 16; n++) {
      float dA = __expf(dl * Ac[n]);
      h[n] = dA * h[n] + w * sB[l][n];
      ya += h[n] * sC[l][n];
    }
    float zz = xz[(size_t)(b * LL + c * LC + l) * (2 * DI) + DI + d];
    y[rowbase + (size_t)l * DI] = f2bf((ya + u * Dv) * silu_f(zz));
  }
}

extern "C" void kernel_launch(void* const* d_in, const int* in_sizes, int n_in,
                              void* d_out, int out_size, void* d_ws, size_t ws_size,
                              hipStream_t stream)
{
  const float* x    = (const float*)d_in[0];
  const float* Win  = (const float*)d_in[1];
  const float* cw   = (const float*)d_in[2];
  const float* cb   = (const float*)d_in[3];
  const float* Wxp  = (const float*)d_in[4];
  const float* Wdt  = (const float*)d_in[5];
  const float* bdt  = (const float*)d_in[6];
  const float* Alog = (const float*)d_in[7];
  const float* Dp   = (const float*)d_in[8];
  const float* Wout = (const float*)d_in[9];
  float* out = (float*)d_out;

  float* ws = (float*)d_ws;
  float* xz     = ws;                        // 16,777,216 f
  float* dlt    = xz + 16777216;             //  8,388,608 f
  float* bcb    = dlt + 8388608;             //    131,072 f
  float* S_arr  = bcb + 131072;              //  4,194,304 f
  float* sumdlt = S_arr + 4194304;           //    262,144 f
  unsigned short* xa_bf = (unsigned short*)(sumdlt + 262144); // 8,388,608 us
  unsigned short* y_bf  = xa_bf + 8388608;   // 8,388,608 us
  unsigned short* x_bf  = y_bf;              // alias: x_bf dead before scan_part2 writes y
  unsigned short* wbuf  = y_bf + 8388608;    // 4,194,304 us (reused per-GEMM weight)
  unsigned short* wxp_bf= wbuf + 4194304;    //     65,536 us

  dim3 blk(256);
  // convert x and in_proj_w to bf16
  f2b_k<<<dim3(BL*DM/2048), blk, 0, stream>>>(x, x_bf, BL*DM);
  f2b_k<<<dim3(2*DI*DM/2048), blk, 0, stream>>>(Win, wbuf, 2*DI*DM);
  // 1) xz = x @ in_proj_w^T   [4096 x 4096], K=1024
  gemm_bt_mfma<0><<<dim3((2*DI)/128, BL/128), blk, 0, stream>>>(x_bf, wbuf, nullptr, xz, BL, 2*DI, DM);
  // 2) x_act = silu(causal_conv(x_ssm)) -> bf16
  conv_silu_k<<<dim3((BL*DI)/256), blk, 0, stream>>>(xz, cw, cb, xa_bf);
  // 3) delta = softplus(x_act @ dt_proj_w^T + b)   [4096 x 2048], K=2048
  f2b_k<<<dim3(DI*DI/2048), blk, 0, stream>>>(Wdt, wbuf, DI*DI);
  gemm_bt_mfma<1><<<dim3(DI/128, BL/128), blk, 0, stream>>>(xa_bf, wbuf, bdt, dlt, BL, DI, DI);
  // 4) bc = x_act @ x_proj_w^T   [4096 x 32]
  f2b_k<<<dim3(2*DS*DI/2048), blk, 0, stream>>>(Wxp, wxp_bf, 2*DS*DI);
  bc_k<<<dim3(BL), blk, 0, stream>>>(xa_bf, wxp_bf, bcb);
  // 5) chunked selective scan
  scan_part1<<<dim3(NB*NC*8), blk, 0, stream>>>(dlt, xa_bf, bcb, Alog, S_arr, sumdlt);
  scan_combine<<<dim3(NB*DI*DS/256), blk, 0, stream>>>(Alog, sumdlt, S_arr);
  scan_part2<<<dim3(NB*NC*8), blk, 0, stream>>>(dlt, xa_bf, bcb, Alog, Dp, xz, S_arr, y_bf);
  // 6) out = y @ out_proj_w^T   [4096 x 1024], K=2048
  f2b_k<<<dim3(DM*DI/2048), blk, 0, stream>>>(Wout, wbuf, DM*DI);
  gemm_bt_mfma<0><<<dim3(DM/128, BL/128), blk, 0, stream>>>(y_bf, wbuf, nullptr, out, BL, DM, DI);
}

// Round 3
// 378.200 us; speedup vs baseline: 5.0359x; 1.1193x over previous
//
#include <hip/hip_runtime.h>
#include <hip/hip_bf16.h>
#include <math.h>

#define DM 1024
#define DS 16
#define DI 2048
#define NB 2
#define LL 2048
#define BL (NB*LL)
#define LC 32
#define NC (LL/LC)   // 64

typedef __attribute__((ext_vector_type(8))) short short8;
typedef __attribute__((ext_vector_type(8))) unsigned short ushort8;
typedef __attribute__((ext_vector_type(4))) float f32x4;

__device__ __forceinline__ float silu_f(float x){ return x / (1.f + __expf(-x)); }
__device__ __forceinline__ float softplus_f(float x){ return (x > 15.f) ? x : log1pf(__expf(x)); }
__device__ __forceinline__ unsigned short f2bf(float f){
  unsigned u = __float_as_uint(f);
  u += 0x7fff + ((u >> 16) & 1);
  return (unsigned short)(u >> 16);
}
__device__ __forceinline__ float bf2f(unsigned short v){
  return __uint_as_float(((unsigned)v) << 16);
}

// ---------------- fp32 -> bf16 convert (8 elems/thread) ----------------
__global__ __launch_bounds__(256) void f2b_k(const float* __restrict__ src,
                                             unsigned short* __restrict__ dst, int n)
{
  int i = (blockIdx.x * 256 + threadIdx.x) * 8;
  if (i >= n) return;
  float4 v0 = *(const float4*)&src[i];
  float4 v1 = *(const float4*)&src[i + 4];
  ushort8 o;
  o[0]=f2bf(v0.x); o[1]=f2bf(v0.y); o[2]=f2bf(v0.z); o[3]=f2bf(v0.w);
  o[4]=f2bf(v1.x); o[5]=f2bf(v1.y); o[6]=f2bf(v1.z); o[7]=f2bf(v1.w);
  *(ushort8*)&dst[i] = o;
}

// ---------------- bf16 MFMA GEMM:  C[M][N] = A[M][K] @ Bw[N][K]^T ------
// 128x128 tile, BK=32, 4 waves, wave tile 64x64 (4x4 frags of 16x16x32)
// EPI==1: v = softplus(v + bias[col])
template<int EPI>
__global__ __launch_bounds__(256) void gemm_bt_mfma(
    const unsigned short* __restrict__ A, const unsigned short* __restrict__ Bw,
    const float* __restrict__ bias, float* __restrict__ C,
    int M, int N, int K)
{
  __shared__ unsigned short As[128 * 32];
  __shared__ unsigned short Bs[128 * 32];
  const int t = threadIdx.x;
  const int wid = t >> 6, lane = t & 63;
  const int bm = blockIdx.y * 128, bn = blockIdx.x * 128;
  const int wm = (wid >> 1) * 64, wn = (wid & 1) * 64;
  f32x4 acc[4][4] = {};

  const int srow = (lane >> 2);          // 0..15 within segment
  const int scol = (lane & 3) * 8;       // k-elem offset of this lane's 16B

  for (int k0 = 0; k0 < K; k0 += 32) {
    __syncthreads();
    #pragma unroll
    for (int q = 0; q < 2; q++) {
      int seg = wid * 2 + q;             // 0..7, wave-uniform
      int row = seg * 16 + srow;
      __builtin_amdgcn_global_load_lds(
          (const __attribute__((address_space(1))) void*)(A + (size_t)(bm + row) * K + k0 + scol),
          (__attribute__((address_space(3))) void*)(As + seg * 512), 16, 0, 0);
      __builtin_amdgcn_global_load_lds(
          (const __attribute__((address_space(1))) void*)(Bw + (size_t)(bn + row) * K + k0 + scol),
          (__attribute__((address_space(3))) void*)(Bs + seg * 512), 16, 0, 0);
    }
    __syncthreads();
    short8 af[4], bfr[4];
    #pragma unroll
    for (int i = 0; i < 4; i++) {
      af[i]  = *(const short8*)&As[(wm + i * 16 + (lane & 15)) * 32 + (lane >> 4) * 8];
      bfr[i] = *(const short8*)&Bs[(wn + i * 16 + (lane & 15)) * 32 + (lane >> 4) * 8];
    }
    #pragma unroll
    for (int i = 0; i < 4; i++)
      #pragma unroll
      for (int j = 0; j < 4; j++)
        acc[i][j] = __builtin_amdgcn_mfma_f32_16x16x32_bf16(af[i], bfr[j], acc[i][j], 0, 0, 0);
  }
  #pragma unroll
  for (int i = 0; i < 4; i++) {
    #pragma unroll
    for (int j = 0; j < 4; j++) {
      int col = bn + wn + j * 16 + (lane & 15);
      #pragma unroll
      for (int r = 0; r < 4; r++) {
        int row = bm + wm + i * 16 + (lane >> 4) * 4 + r;
        float v = acc[i][j][r];
        if (EPI == 1) v = softplus_f(v + bias[col]);
        C[(size_t)row * N + col] = v;
      }
    }
  }
}

// ---------------- causal depthwise conv (k=4) + bias + SiLU -> bf16 ----
__global__ __launch_bounds__(256) void conv_silu_k(
    const float* __restrict__ xz, const float* __restrict__ cw,
    const float* __restrict__ cb, unsigned short* __restrict__ xa)
{
  int idx = blockIdx.x * 256 + threadIdx.x;       // over BL*DI
  int d  = idx & (DI - 1);
  int bl = idx >> 11;
  int l  = bl & (LL - 1);
  float acc = cb[d];
  #pragma unroll
  for (int k = 0; k < 4; k++) {
    int ls = l - 3 + k;
    if (ls >= 0)
      acc += xz[((size_t)(bl - l + ls)) * (2 * DI) + d] * cw[d * 4 + k];
  }
  xa[idx] = f2bf(silu_f(acc));
}

// ---------------- bc = xa @ x_proj_w^T  (N=32) -------------------------
// 8 rows per block staged in LDS (vectorized), thread (m,n) dots row m
// from LDS against weight row n (L2-resident, ushort8 loads).
__global__ __launch_bounds__(256) void bc_k(
    const unsigned short* __restrict__ xa, const unsigned short* __restrict__ w,
    float* __restrict__ bc)
{
  __shared__ unsigned short sx[8 * DI];
  const int t = threadIdx.x;
  const size_t base = (size_t)blockIdx.x * 8 * DI;
  #pragma unroll
  for (int it = 0; it < 8; it++) {
    int v = t + it * 256;                       // vec index over 8*DI/8 = 2048
    *(ushort8*)&sx[v * 8] = *(const ushort8*)&xa[base + (size_t)v * 8];
  }
  __syncthreads();
  const int m = t >> 5, n = t & 31;
  const unsigned short* wr = w + (size_t)n * DI;
  const unsigned short* xr = sx + m * DI;
  float acc = 0.f;
  #pragma unroll 4
  for (int k = 0; k < DI; k += 8) {
    ushort8 xv = *(const ushort8*)&xr[k];
    ushort8 wv = *(const ushort8*)&wr[k];
    #pragma unroll
    for (int j = 0; j < 8; j++) acc += bf2f(xv[j]) * bf2f(wv[j]);
  }
  bc[(size_t)(blockIdx.x * 8 + m) * 32 + n] = acc;
}

// ---------------- chunked selective scan -------------------------------
// pass 1: per (b, chunk, d): local scan (h0=0) -> final local state S[16], sum(delta)
__global__ __launch_bounds__(256) void scan_part1(
    const float* __restrict__ dlt, const unsigned short* __restrict__ xa,
    const float* __restrict__ bc, const float* __restrict__ A_log,
    float* __restrict__ S_arr, float* __restrict__ sumdlt)
{
  const int bid = blockIdx.x;           // NB*NC*8 = 1024
  const int b = bid >> 9;
  const int c = (bid >> 3) & (NC - 1);
  const int dg = bid & 7;
  const int t = threadIdx.x;
  const int d = dg * 256 + t;
  float Ac[16];
  #pragma unroll
  for (int n = 0; n < 16; n++) Ac[n] = -__expf(A_log[d * 16 + n]);
  __shared__ float sB[LC][16];
  for (int e = t; e < LC * 16; e += 256) {
    int l = e >> 4, n = e & 15;
    sB[l][n] = bc[(size_t)(b * LL + c * LC + l) * 32 + n];
  }
  __syncthreads();
  float h[16] = {};
  float sd = 0.f;
  size_t rowbase = (size_t)(b * LL + c * LC) * DI + d;
  for (int l = 0; l < LC; l++) {
    float dl = dlt[rowbase + (size_t)l * DI];
    float u  = bf2f(xa[rowbase + (size_t)l * DI]);
    float w = dl * u;
    sd += dl;
    #pragma unroll
    for (int n = 0; n < 16; n++) {
      float dA = __expf(dl * Ac[n]);
      h[n] = dA * h[n] + w * sB[l][n];
    }
  }
  float* Sp = S_arr + ((size_t)(b * NC + c) * DI + d) * 16;
  #pragma unroll
  for (int n = 0; n < 16; n++) Sp[n] = h[n];
  sumdlt[(size_t)(b * NC + c) * DI + d] = sd;
}

// pass 2: scan chunk summaries; overwrite S_arr with incoming state h_in per chunk
__global__ __launch_bounds__(256) void scan_combine(
    const float* __restrict__ A_log, const float* __restrict__ sumdlt,
    float* __restrict__ S_arr)
{
  int tid = blockIdx.x * 256 + threadIdx.x;   // NB*DI*16 = 65536
  int n = tid & 15;
  int d = (tid >> 4) & (DI - 1);
  int b = tid >> 15;
  float Ac = -__expf(A_log[d * 16 + n]);
  float h = 0.f;
  for (int c = 0; c < NC; c++) {
    size_t idx = ((size_t)(b * NC + c) * DI + d) * 16 + n;
    float S = S_arr[idx];
    float P = __expf(sumdlt[(size_t)(b * NC + c) * DI + d] * Ac);
    S_arr[idx] = h;
    h = P * h + S;
  }
}

// pass 3: recompute local scan with proper h_in, emit y = (h.C + u*D)*silu(z) in bf16
__global__ __launch_bounds__(256) void scan_part2(
    const float* __restrict__ dlt, const unsigned short* __restrict__ xa,
    const float* __restrict__ bc, const float* __restrict__ A_log,
    const float* __restrict__ Dp, const float* __restrict__ xz,
    const float* __restrict__ Hin, unsigned short* __restrict__ y)
{
  const int bid = blockIdx.x;
  const int b = bid >> 9;
  const int c = (bid >> 3) & (NC - 1);
  const int dg = bid & 7;
  const int t = threadIdx.x;
  const int d = dg * 256 + t;
  float Ac[16];
  #pragma unroll
  for (int n = 0; n < 16; n++) Ac[n] = -__expf(A_log[d * 16 + n]);
  __shared__ float sB[LC][16];
  __shared__ float sC[LC][16];
  for (int e = t; e < LC * 16; e += 256) {
    int l = e >> 4, n = e & 15;
    size_t row = (size_t)(b * LL + c * LC + l) * 32;
    sB[l][n] = bc[row + n];
    sC[l][n] = bc[row + 16 + n];
  }
  __syncthreads();
  float h[16];
  const float* Hp = Hin + ((size_t)(b * NC + c) * DI + d) * 16;
  #pragma unroll
  for (int n = 0; n < 16; n++) h[n] = Hp[n];
  const float Dv = Dp[d];
  size_t rowbase = (size_t)(b * LL + c * LC) * DI + d;
  for (int l = 0; l < LC; l++) {
    float dl = dlt[rowbase + (size_t)l * DI];
    float u  = bf2f(xa[rowbase + (size_t)l * DI]);
    float w = dl * u;
    float ya = 0.f;
    #pragma unroll
    for (int n = 0; n < 16; n++) {
      float dA = __expf(dl * Ac[n]);
      h[n] = dA * h[n] + w * sB[l][n];
      ya += h[n] * sC[l][n];
    }
    float zz = xz[(size_t)(b * LL + c * LC + l) * (2 * DI) + DI + d];
    y[rowbase + (size_t)l * DI] = f2bf((ya + u * Dv) * silu_f(zz));
  }
}

extern "C" void kernel_launch(void* const* d_in, const int* in_sizes, int n_in,
                              void* d_out, int out_size, void* d_ws, size_t ws_size,
                              hipStream_t stream)
{
  const float* x    = (const float*)d_in[0];
  const float* Win  = (const float*)d_in[1];
  const float* cw   = (const float*)d_in[2];
  const float* cb   = (const float*)d_in[3];
  const float* Wxp  = (const float*)d_in[4];
  const float* Wdt  = (const float*)d_in[5];
  const float* bdt  = (const float*)d_in[6];
  const float* Alog = (const float*)d_in[7];
  const float* Dp   = (const float*)d_in[8];
  const float* Wout = (const float*)d_in[9];
  float* out = (float*)d_out;

  float* ws = (float*)d_ws;
  float* xz     = ws;                        // 16,777,216 f
  float* dlt    = xz + 16777216;             //  8,388,608 f
  float* bcb    = dlt + 8388608;             //    131,072 f
  float* S_arr  = bcb + 131072;              //  4,194,304 f
  float* sumdlt = S_arr + 4194304;           //    262,144 f
  unsigned short* xa_bf = (unsigned short*)(sumdlt + 262144); // 8,388,608 us
  unsigned short* y_bf  = xa_bf + 8388608;   // 8,388,608 us
  unsigned short* x_bf  = y_bf;              // alias: x_bf dead before scan_part2 writes y
  unsigned short* wbuf  = y_bf + 8388608;    // 4,194,304 us (reused per-GEMM weight)
  unsigned short* wxp_bf= wbuf + 4194304;    //     65,536 us

  dim3 blk(256);
  // convert x and in_proj_w to bf16
  f2b_k<<<dim3(BL*DM/2048), blk, 0, stream>>>(x, x_bf, BL*DM);
  f2b_k<<<dim3(2*DI*DM/2048), blk, 0, stream>>>(Win, wbuf, 2*DI*DM);
  // 1) xz = x @ in_proj_w^T   [4096 x 4096], K=1024
  gemm_bt_mfma<0><<<dim3((2*DI)/128, BL/128), blk, 0, stream>>>(x_bf, wbuf, nullptr, xz, BL, 2*DI, DM);
  // 2) x_act = silu(causal_conv(x_ssm)) -> bf16
  conv_silu_k<<<dim3((BL*DI)/256), blk, 0, stream>>>(xz, cw, cb, xa_bf);
  // 3) delta = softplus(x_act @ dt_proj_w^T + b)   [4096 x 2048], K=2048
  f2b_k<<<dim3(DI*DI/2048), blk, 0, stream>>>(Wdt, wbuf, DI*DI);
  gemm_bt_mfma<1><<<dim3(DI/128, BL/128), blk, 0, stream>>>(xa_bf, wbuf, bdt, dlt, BL, DI, DI);
  // 4) bc = x_act @ x_proj_w^T   [4096 x 32]
  f2b_k<<<dim3(2*DS*DI/2048), blk, 0, stream>>>(Wxp, wxp_bf, 2*DS*DI);
  bc_k<<<dim3(BL/8), blk, 0, stream>>>(xa_bf, wxp_bf, bcb);
  // 5) chunked selective scan
  scan_part1<<<dim3(NB*NC*8), blk, 0, stream>>>(dlt, xa_bf, bcb, Alog, S_arr, sumdlt);
  scan_combine<<<dim3(NB*DI*DS/256), blk, 0, stream>>>(Alog, sumdlt, S_arr);
  scan_part2<<<dim3(NB*NC*8), blk, 0, stream>>>(dlt, xa_bf, bcb, Alog, Dp, xz, S_arr, y_bf);
  // 6) out = y @ out_proj_w^T   [4096 x 1024], K=2048
  f2b_k<<<dim3(DM*DI/2048), blk, 0, stream>>>(Wout, wbuf, DM*DI);
  gemm_bt_mfma<0><<<dim3(DM/128, BL/128), blk, 0, stream>>>(y_bf, wbuf, nullptr, out, BL, DM, DI);
}

// Round 4
// 325.012 us; speedup vs baseline: 5.8600x; 1.1636x over previous
//
#include <hip/hip_runtime.h>
#include <hip/hip_bf16.h>
#include <math.h>

#define DM 1024
#define DS 16
#define DI 2048
#define NB 2
#define LL 2048
#define BL (NB*LL)
#define LC 32
#define NC (LL/LC)   // 64

typedef __attribute__((ext_vector_type(8))) short short8;
typedef __attribute__((ext_vector_type(8))) unsigned short ushort8;
typedef __attribute__((ext_vector_type(4))) float f32x4;

__device__ __forceinline__ float silu_f(float x){ return x / (1.f + __expf(-x)); }
__device__ __forceinline__ float softplus_f(float x){ return (x > 15.f) ? x : log1pf(__expf(x)); }
__device__ __forceinline__ unsigned short f2bf(float f){
  unsigned u = __float_as_uint(f);
  u += 0x7fff + ((u >> 16) & 1);
  return (unsigned short)(u >> 16);
}
__device__ __forceinline__ float bf2f(unsigned short v){
  return __uint_as_float(((unsigned)v) << 16);
}

// ---------------- fp32 -> bf16 convert (8 elems/thread) ----------------
__global__ __launch_bounds__(256) void f2b_k(const float* __restrict__ src,
                                             unsigned short* __restrict__ dst, int n)
{
  int i = (blockIdx.x * 256 + threadIdx.x) * 8;
  if (i >= n) return;
  float4 v0 = *(const float4*)&src[i];
  float4 v1 = *(const float4*)&src[i + 4];
  ushort8 o;
  o[0]=f2bf(v0.x); o[1]=f2bf(v0.y); o[2]=f2bf(v0.z); o[3]=f2bf(v0.w);
  o[4]=f2bf(v1.x); o[5]=f2bf(v1.y); o[6]=f2bf(v1.z); o[7]=f2bf(v1.w);
  *(ushort8*)&dst[i] = o;
}

// ---------------- 256-row-tile bf16 MFMA GEMM, 8 waves, dbuf LDS -------
// C[M][N] = A[M][K] @ Bw[N][K]^T.  BM=256, BK=64, BN in {256,128,64}.
// 8 waves as 2(M) x 4(N): per-wave 128 x BN/4.
// LDS XOR-swizzle: chunk' = chunk ^ (row&7) applied on BOTH the staged
// global source and the ds_read (rule 21: same involution both sides).
// Stage for tile t+1 issued BEFORE compute of tile t; single
// vmcnt(0)+barrier (__syncthreads) per K-step (T3 minimal recipe).
// EPI==1: v = softplus(v + bias[col]).  OUTBF: store bf16 else fp32.
template<int BN, int EPI, int OUTBF>
__global__ __launch_bounds__(512, 2) void gemm2(
    const unsigned short* __restrict__ A, const unsigned short* __restrict__ Bw,
    const float* __restrict__ bias, void* __restrict__ Cp,
    int M, int N, int K)
{
  constexpr int BM = 256;
  constexpr int NR = BN / 64;                 // N-frags per wave: 4/2/1
  __shared__ unsigned short lds[2][(BM + BN) * 64];
  const int t = threadIdx.x;
  const int wid = t >> 6, lane = t & 63;
  const int nbx = N / BN;
  const int cpx = (nbx * (M / BM)) >> 3;      // grid always 256 -> cpx=32
  const int bid = (int)blockIdx.x;
  const int swz = (bid & 7) * cpx + (bid >> 3);   // XCD-contiguous logical tiles
  const int bm = (swz / nbx) * BM, bn = (swz % nbx) * BN;
  const int wm = (wid >> 2) * 128, wn = (wid & 3) * (BN / 4);
  const int srow8 = lane >> 3;                // 0..7
  const int sch   = lane & 7;                 // 16B chunk 0..7

  f32x4 acc[8][NR] = {};

  auto stage = [&](int buf, int k0) {
    #pragma unroll
    for (int p = 0; p < BM / 64; p++) {
      int row = p * 64 + wid * 8 + srow8;
      int ch = sch ^ (row & 7);
      __builtin_amdgcn_global_load_lds(
        (const __attribute__((address_space(1))) void*)(A + (size_t)(bm + row) * K + k0 + ch * 8),
        (__attribute__((address_space(3))) void*)(&lds[buf][(p * 64 + wid * 8) * 64]), 16, 0, 0);
    }
    #pragma unroll
    for (int p = 0; p < BN / 64; p++) {
      int row = p * 64 + wid * 8 + srow8;
      int ch = sch ^ (row & 7);
      __builtin_amdgcn_global_load_lds(
        (const __attribute__((address_space(1))) void*)(Bw + (size_t)(bn + row) * K + k0 + ch * 8),
        (__attribute__((address_space(3))) void*)(&lds[buf][(BM + p * 64 + wid * 8) * 64]), 16, 0, 0);
    }
  };

  stage(0, 0);
  __syncthreads();
  const int nk = K / 64;
  int cur = 0;
  for (int kt = 0; kt < nk; kt++) {
    if (kt + 1 < nk) stage(cur ^ 1, (kt + 1) * 64);   // overlap with MFMA below
    const unsigned short* bufA = &lds[cur][0];
    const unsigned short* bufB = &lds[cur][BM * 64];
    #pragma unroll
    for (int ks = 0; ks < 2; ks++) {
      short8 af[8], bfr[NR];
      #pragma unroll
      for (int i = 0; i < 8; i++) {
        int r = wm + i * 16 + (lane & 15);
        int c = ((ks << 2) + (lane >> 4)) ^ (r & 7);
        af[i] = *(const short8*)&bufA[r * 64 + c * 8];
      }
      #pragma unroll
      for (int j = 0; j < NR; j++) {
        int r = wn + j * 16 + (lane & 15);
        int c = ((ks << 2) + (lane >> 4)) ^ (r & 7);
        bfr[j] = *(const short8*)&bufB[r * 64 + c * 8];
      }
      #pragma unroll
      for (int i = 0; i < 8; i++)
        #pragma unroll
        for (int j = 0; j < NR; j++)
          acc[i][j] = __builtin_amdgcn_mfma_f32_16x16x32_bf16(af[i], bfr[j], acc[i][j], 0, 0, 0);
    }
    __syncthreads();                // drains vmcnt(0)+lgkmcnt(0) then barrier
    cur ^= 1;
  }
  #pragma unroll
  for (int i = 0; i < 8; i++) {
    #pragma unroll
    for (int j = 0; j < NR; j++) {
      int col = bn + wn + j * 16 + (lane & 15);
      float bv = (EPI == 1) ? bias[col] : 0.f;
      #pragma unroll
      for (int r = 0; r < 4; r++) {
        int row = bm + wm + i * 16 + (lane >> 4) * 4 + r;
        float v = acc[i][j][r];
        if (EPI == 1) v = softplus_f(v + bv);
        if (OUTBF) ((unsigned short*)Cp)[(size_t)row * N + col] = f2bf(v);
        else       ((float*)Cp)[(size_t)row * N + col] = v;
      }
    }
  }
}

// ---------------- causal depthwise conv (k=4) + bias + SiLU -> bf16 ----
__global__ __launch_bounds__(256) void conv_silu_k(
    const unsigned short* __restrict__ xz, const float* __restrict__ cw,
    const float* __restrict__ cb, unsigned short* __restrict__ xa)
{
  int idx = blockIdx.x * 256 + threadIdx.x;       // over BL*DI
  int d  = idx & (DI - 1);
  int bl = idx >> 11;
  int l  = bl & (LL - 1);
  float acc = cb[d];
  #pragma unroll
  for (int k = 0; k < 4; k++) {
    int ls = l - 3 + k;
    if (ls >= 0)
      acc += bf2f(xz[((size_t)(bl - l + ls)) * (2 * DI) + d]) * cw[d * 4 + k];
  }
  xa[idx] = f2bf(silu_f(acc));
}

// ---------------- bc = xa @ x_proj_w^T  (N=32) -------------------------
__global__ __launch_bounds__(256) void bc_k(
    const unsigned short* __restrict__ xa, const unsigned short* __restrict__ w,
    float* __restrict__ bc)
{
  __shared__ unsigned short sx[8 * DI];
  const int t = threadIdx.x;
  const size_t base = (size_t)blockIdx.x * 8 * DI;
  #pragma unroll
  for (int it = 0; it < 8; it++) {
    int v = t + it * 256;
    *(ushort8*)&sx[v * 8] = *(const ushort8*)&xa[base + (size_t)v * 8];
  }
  __syncthreads();
  const int m = t >> 5, n = t & 31;
  const unsigned short* wr = w + (size_t)n * DI;
  const unsigned short* xr = sx + m * DI;
  float acc = 0.f;
  #pragma unroll 4
  for (int k = 0; k < DI; k += 8) {
    ushort8 xv = *(const ushort8*)&xr[k];
    ushort8 wv = *(const ushort8*)&wr[k];
    #pragma unroll
    for (int j = 0; j < 8; j++) acc += bf2f(xv[j]) * bf2f(wv[j]);
  }
  bc[(size_t)(blockIdx.x * 8 + m) * 32 + n] = acc;
}

// ---------------- chunked selective scan -------------------------------
__global__ __launch_bounds__(256) void scan_part1(
    const float* __restrict__ dlt, const unsigned short* __restrict__ xa,
    const float* __restrict__ bc, const float* __restrict__ A_log,
    float* __restrict__ S_arr, float* __restrict__ sumdlt)
{
  const int bid = blockIdx.x;           // NB*NC*8 = 1024
  const int b = bid >> 9;
  const int c = (bid >> 3) & (NC - 1);
  const int dg = bid & 7;
  const int t = threadIdx.x;
  const int d = dg * 256 + t;
  float Ac[16];
  #pragma unroll
  for (int n = 0; n < 16; n++) Ac[n] = -__expf(A_log[d * 16 + n]);
  __shared__ float sB[LC][16];
  for (int e = t; e < LC * 16; e += 256) {
    int l = e >> 4, n = e & 15;
    sB[l][n] = bc[(size_t)(b * LL + c * LC + l) * 32 + n];
  }
  __syncthreads();
  float h[16] = {};
  float sd = 0.f;
  size_t rowbase = (size_t)(b * LL + c * LC) * DI + d;
  for (int l = 0; l < LC; l++) {
    float dl = dlt[rowbase + (size_t)l * DI];
    float u  = bf2f(xa[rowbase + (size_t)l * DI]);
    float w = dl * u;
    sd += dl;
    #pragma unroll
    for (int n = 0; n < 16; n++) {
      float dA = __expf(dl * Ac[n]);
      h[n] = dA * h[n] + w * sB[l][n];
    }
  }
  float* Sp = S_arr + ((size_t)(b * NC + c) * DI + d) * 16;
  #pragma unroll
  for (int n = 0; n < 16; n++) Sp[n] = h[n];
  sumdlt[(size_t)(b * NC + c) * DI + d] = sd;
}

__global__ __launch_bounds__(256) void scan_combine(
    const float* __restrict__ A_log, const float* __restrict__ sumdlt,
    float* __restrict__ S_arr)
{
  int tid = blockIdx.x * 256 + threadIdx.x;   // NB*DI*16 = 65536
  int n = tid & 15;
  int d = (tid >> 4) & (DI - 1);
  int b = tid >> 15;
  float Ac = -__expf(A_log[d * 16 + n]);
  float h = 0.f;
  for (int c = 0; c < NC; c++) {
    size_t idx = ((size_t)(b * NC + c) * DI + d) * 16 + n;
    float S = S_arr[idx];
    float P = __expf(sumdlt[(size_t)(b * NC + c) * DI + d] * Ac);
    S_arr[idx] = h;
    h = P * h + S;
  }
}

__global__ __launch_bounds__(256) void scan_part2(
    const float* __restrict__ dlt, const unsigned short* __restrict__ xa,
    const float* __restrict__ bc, const float* __restrict__ A_log,
    const float* __restrict__ Dp, const unsigned short* __restrict__ xz,
    const float* __restrict__ Hin, unsigned short* __restrict__ y)
{
  const int bid = blockIdx.x;
  const int b = bid >> 9;
  const int c = (bid >> 3) & (NC - 1);
  const int dg = bid & 7;
  const int t = threadIdx.x;
  const int d = dg * 256 + t;
  float Ac[16];
  #pragma unroll
  for (int n = 0; n < 16; n++) Ac[n] = -__expf(A_log[d * 16 + n]);
  __shared__ float sB[LC][16];
  __shared__ float sC[LC][16];
  for (int e = t; e < LC * 16; e += 256) {
    int l = e >> 4, n = e & 15;
    size_t row = (size_t)(b * LL + c * LC + l) * 32;
    sB[l][n] = bc[row + n];
    sC[l][n] = bc[row + 16 + n];
  }
  __syncthreads();
  float h[16];
  const float* Hp = Hin + ((size_t)(b * NC + c) * DI + d) * 16;
  #pragma unroll
  for (int n = 0; n < 16; n++) h[n] = Hp[n];
  const float Dv = Dp[d];
  size_t rowbase = (size_t)(b * LL + c * LC) * DI + d;
  for (int l = 0; l < LC; l++) {
    float dl = dlt[rowbase + (size_t)l * DI];
    float u  = bf2f(xa[rowbase + (size_t)l * DI]);
    float w = dl * u;
    float ya = 0.f;
    #pragma unroll
    for (int n = 0; n < 16; n++) {
      float dA = __expf(dl * Ac[n]);
      h[n] = dA * h[n] + w * sB[l][n];
      ya += h[n] * sC[l][n];
    }
    float zz = bf2f(xz[(size_t)(b * LL + c * LC + l) * (2 * DI) + DI + d]);
    y[rowbase + (size_t)l * DI] = f2bf((ya + u * Dv) * silu_f(zz));
  }
}

extern "C" void kernel_launch(void* const* d_in, const int* in_sizes, int n_in,
                              void* d_out, int out_size, void* d_ws, size_t ws_size,
                              hipStream_t stream)
{
  const float* x    = (const float*)d_in[0];
  const float* Win  = (const float*)d_in[1];
  const float* cw   = (const float*)d_in[2];
  const float* cb   = (const float*)d_in[3];
  const float* Wxp  = (const float*)d_in[4];
  const float* Wdt  = (const float*)d_in[5];
  const float* bdt  = (const float*)d_in[6];
  const float* Alog = (const float*)d_in[7];
  const float* Dp   = (const float*)d_in[8];
  const float* Wout = (const float*)d_in[9];
  float* out = (float*)d_out;

  float* ws = (float*)d_ws;
  float* dlt    = ws;                        //  8,388,608 f
  float* bcb    = dlt + 8388608;             //    131,072 f
  float* S_arr  = bcb + 131072;              //  4,194,304 f
  float* sumdlt = S_arr + 4194304;           //    262,144 f
  unsigned short* xz_bf = (unsigned short*)(sumdlt + 262144); // 16,777,216 us
  unsigned short* xa_bf = xz_bf + 16777216;  //  8,388,608 us
  unsigned short* y_bf  = xa_bf + 8388608;   //  8,388,608 us
  unsigned short* x_bf  = y_bf;              // alias: dead before scan_part2 writes y
  unsigned short* wbuf  = y_bf + 8388608;    //  4,194,304 us
  unsigned short* wxp_bf= wbuf + 4194304;    //     65,536 us

  dim3 blk(256);
  // convert x and in_proj_w to bf16
  f2b_k<<<dim3(BL*DM/2048), blk, 0, stream>>>(x, x_bf, BL*DM);
  f2b_k<<<dim3(2*DI*DM/2048), blk, 0, stream>>>(Win, wbuf, 2*DI*DM);
  // 1) xz = x @ in_proj_w^T   [4096 x 4096], K=1024 -> bf16
  gemm2<256,0,1><<<dim3(256), dim3(512), 0, stream>>>(x_bf, wbuf, nullptr, xz_bf, BL, 2*DI, DM);
  // 2) x_act = silu(causal_conv(x_ssm)) -> bf16
  conv_silu_k<<<dim3((BL*DI)/256), blk, 0, stream>>>(xz_bf, cw, cb, xa_bf);
  // 3) delta = softplus(x_act @ dt_proj_w^T + b)   [4096 x 2048], K=2048 -> fp32
  f2b_k<<<dim3(DI*DI/2048), blk, 0, stream>>>(Wdt, wbuf, DI*DI);
  gemm2<128,1,0><<<dim3(256), dim3(512), 0, stream>>>(xa_bf, wbuf, bdt, dlt, BL, DI, DI);
  // 4) bc = x_act @ x_proj_w^T   [4096 x 32]
  f2b_k<<<dim3(2*DS*DI/2048), blk, 0, stream>>>(Wxp, wxp_bf, 2*DS*DI);
  bc_k<<<dim3(BL/8), blk, 0, stream>>>(xa_bf, wxp_bf, bcb);
  // 5) chunked selective scan
  scan_part1<<<dim3(NB*NC*8), blk, 0, stream>>>(dlt, xa_bf, bcb, Alog, S_arr, sumdlt);
  scan_combine<<<dim3(NB*DI*DS/256), blk, 0, stream>>>(Alog, sumdlt, S_arr);
  scan_part2<<<dim3(NB*NC*8), blk, 0, stream>>>(dlt, xa_bf, bcb, Alog, Dp, xz_bf, S_arr, y_bf);
  // 6) out = y @ out_proj_w^T   [4096 x 1024], K=2048 -> fp32
  f2b_k<<<dim3(DM*DI/2048), blk, 0, stream>>>(Wout, wbuf, DM*DI);
  gemm2<64,0,0><<<dim3(256), dim3(512), 0, stream>>>(y_bf, wbuf, nullptr, out, BL, DM, DI);
}